// Round 6
// baseline (344.490 us; speedup 1.0000x reference)
//
#include <hip/hip_runtime.h>
#include <hip/hip_bf16.h>

#define BB 16
#define NN 10
#define CC 128
#define HWD 2304            // 48*48
#define DD (CC*HWD)         // 294912
#define NC (NN*CC)          // 1280
#define CHK 36              // chunks per (b,n) for dot kernel
#define CHUNK (DD/CHK)      // 8192

#define BM 128
#define BN 128
#define BK 64
#define TK (NC/BK)          // 20 K-tiles

typedef __bf16 bf16x8 __attribute__((ext_vector_type(8)));
typedef float  f32x4  __attribute__((ext_vector_type(4)));

#define FEAT_BYTES ((size_t)BB*HWD*NC*2)     // 94,371,840
#define WB_BYTES   ((size_t)NC*NC*2)         // 3,276,800
#define PART_FLOATS (BB*NN*CHK*3)            // 17,280

__device__ __forceinline__ ushort f2bf(float f) {
    __hip_bfloat16 h = __float2bfloat16(f);
    return *reinterpret_cast<ushort*>(&h);
}

__device__ __forceinline__ void gload_lds16(const ushort* g, ushort* l) {
    __builtin_amdgcn_global_load_lds(
        (const __attribute__((address_space(1))) void*)(const void*)g,
        (__attribute__((address_space(3))) void*)(void*)l,
        16, 0, 0);
}

// ---------------- Kernel 1: partial dots d0,d1,d2 ----------------
__global__ __launch_bounds__(256) void k_dots(const float* __restrict__ x,
                                              float* __restrict__ part) {
    int blk = blockIdx.x;
    int n  = blk % NN;
    int rest = blk / NN;
    int ch = rest % CHK;
    int b  = rest / CHK;
    int bn = b*NN + n;
    int n1 = (n + 1) % NN, n2 = (n + 2) % NN;
    const float* p0 = x + ((size_t)b*NN + n )*DD + (size_t)ch*CHUNK;
    const float* p1 = x + ((size_t)b*NN + n1)*DD + (size_t)ch*CHUNK;
    const float* p2 = x + ((size_t)b*NN + n2)*DD + (size_t)ch*CHUNK;
    int t = threadIdx.x;
    float s0 = 0.f, s1 = 0.f, s2 = 0.f;
    #pragma unroll
    for (int i = 0; i < CHUNK/1024; ++i) {
        int off = i*1024 + t*4;
        float4 a = *(const float4*)(p0 + off);
        float4 u = *(const float4*)(p1 + off);
        float4 v = *(const float4*)(p2 + off);
        s0 += a.x*a.x + a.y*a.y + a.z*a.z + a.w*a.w;
        s1 += a.x*u.x + a.y*u.y + a.z*u.z + a.w*u.w;
        s2 += a.x*v.x + a.y*v.y + a.z*v.z + a.w*v.w;
    }
    for (int o = 32; o > 0; o >>= 1) {
        s0 += __shfl_down(s0, o);
        s1 += __shfl_down(s1, o);
        s2 += __shfl_down(s2, o);
    }
    __shared__ float red[4][3];
    int w = t >> 6, l = t & 63;
    if (l == 0) { red[w][0] = s0; red[w][1] = s1; red[w][2] = s2; }
    __syncthreads();
    if (t == 0) {
        float r0 = 0.f, r1 = 0.f, r2 = 0.f;
        for (int i = 0; i < 4; ++i) { r0 += red[i][0]; r1 += red[i][1]; r2 += red[i][2]; }
        float* o = part + ((size_t)bn*CHK + ch)*3;
        o[0] = r0; o[1] = r1; o[2] = r2;
    }
}

// ---------------- Kernel 2: softmax -> combination coefficients ----------------
__global__ void k_coef(const float* __restrict__ part,
                       const float* __restrict__ pos_dec,
                       const float* __restrict__ len_dec,
                       float* __restrict__ coef) {
    int bn = threadIdx.x;
    if (bn >= BB*NN) return;
    int n = bn % NN;
    float d0 = 0.f, d1 = 0.f, d2 = 0.f;
    const float* p = part + (size_t)bn*CHK*3;
    for (int i = 0; i < CHK; ++i) { d0 += p[i*3]; d1 += p[i*3+1]; d2 += p[i*3+2]; }
    float pd = pos_dec[n], ld = len_dec[n];
    float l0 = (1.f - pd)*d0 + pd*d1;
    float l1 = ld*((1.f - pd)*d1 + pd*d2);
    float m  = fmaxf(l0, l1);
    float e0 = expf(l0 - m), e1 = expf(l1 - m);
    float inv = 1.f/(e0 + e1);
    float a0 = e0*inv, a1 = e1*inv;
    coef[bn*3+0] = a0*(1.f - pd);
    coef[bn*3+1] = a0*pd + a1*ld*(1.f - pd);
    coef[bn*3+2] = a1*ld*pd;
}

// ---------------- Kernel 3: conv_w fp32 -> bf16 ----------------
__global__ __launch_bounds__(256) void k_wconv(const float* __restrict__ w,
                                               ushort* __restrict__ wb) {
    int i = blockIdx.x*blockDim.x + threadIdx.x;
    size_t idx = (size_t)i*4;
    if (idx >= (size_t)NC*NC) return;
    float4 a = *(const float4*)(w + idx);
    ushort4 o;
    o.x = f2bf(a.x); o.y = f2bf(a.y); o.z = f2bf(a.z); o.w = f2bf(a.w);
    *(ushort4*)(wb + idx) = o;
}

// ---------------- Kernel 4: featT[b][hw][c] bf16 (transposed combo) ----------------
__global__ __launch_bounds__(256) void k_feat(const float* __restrict__ x,
                                              const float* __restrict__ coef,
                                              ushort* __restrict__ featT) {
    __shared__ float tile[32*129];
    int hwt = blockIdx.x;         // 0..71
    int n   = blockIdx.y;         // 0..9
    int b   = blockIdx.z;         // 0..15
    int bn  = b*NN + n;
    float c0 = coef[bn*3+0], c1 = coef[bn*3+1], c2 = coef[bn*3+2];
    int n1 = (n + 1) % NN, n2 = (n + 2) % NN;
    const float* p0 = x + ((size_t)b*NN + n )*DD;
    const float* p1 = x + ((size_t)b*NN + n1)*DD;
    const float* p2 = x + ((size_t)b*NN + n2)*DD;
    int t = threadIdx.x;
    int hw0 = hwt*32;

    int ccl = t >> 3;             // 0..31
    int hwi = (t & 7) * 4;        // 0..28
    #pragma unroll
    for (int p = 0; p < 4; ++p) {
        int cc = p*32 + ccl;
        size_t off = (size_t)cc*HWD + hw0 + hwi;
        float4 a = *(const float4*)(p0 + off);
        float4 u = *(const float4*)(p1 + off);
        float4 v = *(const float4*)(p2 + off);
        tile[(hwi+0)*129 + cc] = c0*a.x + c1*u.x + c2*v.x;
        tile[(hwi+1)*129 + cc] = c0*a.y + c1*u.y + c2*v.y;
        tile[(hwi+2)*129 + cc] = c0*a.z + c1*u.z + c2*v.z;
        tile[(hwi+3)*129 + cc] = c0*a.w + c1*u.w + c2*v.w;
    }
    __syncthreads();

    int hwl = t >> 4;             // 0..15
    int cc0 = (t & 15) * 8;       // 0..120
    #pragma unroll
    for (int p = 0; p < 2; ++p) {
        int hw = p*16 + hwl;
        const float* src = &tile[hw*129 + cc0];
        union { ushort us[8]; uint4 v; } pk;
        #pragma unroll
        for (int j = 0; j < 8; ++j) pk.us[j] = f2bf(src[j]);
        ushort* dst = featT + (size_t)b*HWD*NC + (size_t)(hw0 + hw)*NC + n*CC + cc0;
        *(uint4*)dst = pk.v;
    }
}

// ---------------- Kernel 5: 128x128x64 GEMM, 2 blocks/CU, m97-style loop ----------------
// LDS per operand tile: [128 rows][8 chunks of 16B], phys_chunk = c ^ (row&7)
// (zero-conflict: a 16-lane fragment read spans 16 rows -> 8 distinct chunks, 2-way max).
// gload_lds dest linear; global source pre-swizzled. One __syncthreads per K-step;
// cross-block TLP (2 blocks/CU) hides the drain.
__global__ __launch_bounds__(256, 2) void k_gemm(const ushort* __restrict__ Wb,
                                                 const ushort* __restrict__ featT,
                                                 const float* __restrict__ bias,
                                                 const float* __restrict__ x,
                                                 float* __restrict__ out) {
    __shared__ ushort L[2][2][BM*BK];   // [buf][A=0/B=1][128*64] = 64 KiB total

    // XCD-chunked mapping, o fastest: per XCD, W (3.3 MB) stays hot in L2,
    // featT panels (320 KB) stream with ~10-block reuse.
    int bid = blockIdx.x;
    int wkid = (bid & 7) * 360 + (bid >> 3);   // 2880 = 8*360, bijective
    int b    = wkid / 180;
    int rem  = wkid % 180;
    int hwt  = rem / 10;
    int ot   = rem % 10;
    int o0 = ot*BM, hw0 = hwt*BN;

    int t = threadIdx.x;
    int l = t & 63;
    int w = t >> 6;
    int wr = w >> 1, wc = w & 1;      // 2x2 wave grid, 64x64 per wave

    const ushort* Ag = Wb + (size_t)o0*NC;
    const ushort* Bg = featT + (size_t)b*HWD*NC + (size_t)hw0*NC;

    // staging: 1024 slots of 16B per operand; thread t covers slots t+256q
    int sr = t >> 3;                  // row of slot t (rows advance +32 per q)
    int sc = t & 7;                   // logical chunk
    size_t gq[4];
    #pragma unroll
    for (int q = 0; q < 4; ++q) {
        int row = sr + 32*q;
        gq[q] = (size_t)row*NC + (size_t)((sc ^ (row & 7)) * 8);
    }

#define STAGE(buf_, kt_) do { \
    size_t ko_ = (size_t)(kt_)*BK; \
    ushort* da_ = &L[buf_][0][0]; \
    ushort* db_ = &L[buf_][1][0]; \
    _Pragma("unroll") \
    for (int q = 0; q < 4; ++q) { \
        gload_lds16(Ag + gq[q] + ko_, da_ + (q*256 + t)*8); \
        gload_lds16(Bg + gq[q] + ko_, db_ + (q*256 + t)*8); \
    } } while (0)

    // fragment read constants
    int fr = l & 15;
    int fc = l >> 4;                  // 0..3 (k sub-chunk within 32-elem k-step)

    f32x4 acc[4][4] = {};

    STAGE(0, 0);
    __syncthreads();

    for (int kt = 0; kt < TK; ++kt) {
        int buf = kt & 1;
        if (kt + 1 < TK) STAGE(buf ^ 1, kt + 1);

        const ushort* as = &L[buf][0][0];
        const ushort* bs = &L[buf][1][0];

        #pragma unroll
        for (int kq = 0; kq < 2; ++kq) {
            bf16x8 afr[4], bfr[4];
            #pragma unroll
            for (int m = 0; m < 4; ++m) {
                int row = wr*64 + m*16 + fr;
                afr[m] = *(const bf16x8*)&as[row*BK + (((kq*4 + fc) ^ (row & 7))*8)];
            }
            #pragma unroll
            for (int n = 0; n < 4; ++n) {
                int row = wc*64 + n*16 + fr;
                bfr[n] = *(const bf16x8*)&bs[row*BK + (((kq*4 + fc) ^ (row & 7))*8)];
            }
            #pragma unroll
            for (int m = 0; m < 4; ++m)
                #pragma unroll
                for (int n = 0; n < 4; ++n)
                    acc[m][n] = __builtin_amdgcn_mfma_f32_16x16x32_bf16(afr[m], bfr[n], acc[m][n], 0, 0, 0);
        }
        __syncthreads();
    }
#undef STAGE

    // epilogue: + bias + residual x
    #pragma unroll
    for (int m = 0; m < 4; ++m) {
        int ro_base = o0 + wr*64 + m*16 + ((l >> 4) << 2);
        #pragma unroll
        for (int n = 0; n < 4; ++n) {
            int col = hw0 + wc*64 + n*16 + (l & 15);
            #pragma unroll
            for (int r = 0; r < 4; ++r) {
                int ro = ro_base + r;
                size_t idx = (size_t)b*NC*HWD + (size_t)ro*HWD + col;
                out[idx] = acc[m][n][r] + bias[ro] + x[idx];
            }
        }
    }
}

extern "C" void kernel_launch(void* const* d_in, const int* in_sizes, int n_in,
                              void* d_out, int out_size, void* d_ws, size_t ws_size,
                              hipStream_t stream) {
    const float* x       = (const float*)d_in[0];
    const float* pos_dec = (const float*)d_in[1];
    const float* len_dec = (const float*)d_in[2];
    const float* conv_w  = (const float*)d_in[3];
    const float* conv_b  = (const float*)d_in[4];
    float* out = (float*)d_out;

    char* ws = (char*)d_ws;
    ushort* featT = (ushort*)ws;                                   // 94,371,840 B
    ushort* wb    = (ushort*)(ws + FEAT_BYTES);                    // 3,276,800 B
    float*  part  = (float*)(ws + FEAT_BYTES + WB_BYTES);          // 69,120 B
    float*  coef  = part + PART_FLOATS;                            // 1,920 B

    k_dots <<<dim3(BB*NN*CHK), 256, 0, stream>>>(x, part);
    k_coef <<<dim3(1), 256, 0, stream>>>(part, pos_dec, len_dec, coef);
    k_wconv<<<dim3(1600), 256, 0, stream>>>(conv_w, wb);
    k_feat <<<dim3(72, NN, BB), 256, 0, stream>>>(x, coef, featT);
    k_gemm <<<dim3(2880), 256, 0, stream>>>(wb, featT, conv_b, x, out);
}

// Round 7
// 315.033 us; speedup vs baseline: 1.0935x; 1.0935x over previous
//
#include <hip/hip_runtime.h>
#include <hip/hip_bf16.h>

#define BB 16
#define NN 10
#define CC 128
#define HWD 2304            // 48*48
#define DD (CC*HWD)         // 294912
#define NC (NN*CC)          // 1280

#define CH2 72              // chunks per b for dot kernel
#define CHUNK2 4096         // floats per chunk

#define BM 128
#define BN 128
#define BK 32
#define TK (NC/BK)          // 40 K-steps

typedef __bf16 bf16x8 __attribute__((ext_vector_type(8)));
typedef float  f32x4  __attribute__((ext_vector_type(4)));

#define FEAT_BYTES ((size_t)BB*HWD*NC*2)     // 94,371,840
#define WB_BYTES   ((size_t)NC*NC*2)         // 3,276,800
#define PART_FLOATS (BB*NN*CH2*3)            // 34,560

__device__ __forceinline__ ushort f2bf(float f) {
    __hip_bfloat16 h = __float2bfloat16(f);
    return *reinterpret_cast<ushort*>(&h);
}

__device__ __forceinline__ void gload_lds16(const ushort* g, ushort* l) {
    __builtin_amdgcn_global_load_lds(
        (const __attribute__((address_space(1))) void*)(const void*)g,
        (__attribute__((address_space(3))) void*)(void*)l,
        16, 0, 0);
}

// ---------------- Kernel 1: dots d0,d1,d2 — single pass over x ----------------
// Block owns (b, chunk). Walks n=0..9 keeping slices n (cur) and n+1 (nxt) in
// registers, streaming slice n+2. x is read ~1.2x once instead of 3x.
__global__ __launch_bounds__(256) void k_dots(const float* __restrict__ x,
                                              float* __restrict__ part) {
    int blk = blockIdx.x;             // 0..BB*CH2-1
    int ch = blk % CH2;
    int b  = blk / CH2;
    const float* base = x + (size_t)b*NN*DD + (size_t)ch*CHUNK2;
    int t = threadIdx.x;

    float4 cur[4], nxt[4], inc[4];
    #pragma unroll
    for (int i = 0; i < 4; ++i) cur[i] = *(const float4*)(base + (size_t)0*DD + i*1024 + t*4);
    #pragma unroll
    for (int i = 0; i < 4; ++i) nxt[i] = *(const float4*)(base + (size_t)1*DD + i*1024 + t*4);

    __shared__ float red[4][3];
    int w = t >> 6, l = t & 63;

    for (int n = 0; n < NN; ++n) {
        int n2 = (n + 2) % NN;
        #pragma unroll
        for (int i = 0; i < 4; ++i) inc[i] = *(const float4*)(base + (size_t)n2*DD + i*1024 + t*4);

        float s0 = 0.f, s1 = 0.f, s2 = 0.f;
        #pragma unroll
        for (int i = 0; i < 4; ++i) {
            s0 += cur[i].x*cur[i].x + cur[i].y*cur[i].y + cur[i].z*cur[i].z + cur[i].w*cur[i].w;
            s1 += cur[i].x*nxt[i].x + cur[i].y*nxt[i].y + cur[i].z*nxt[i].z + cur[i].w*nxt[i].w;
            s2 += cur[i].x*inc[i].x + cur[i].y*inc[i].y + cur[i].z*inc[i].z + cur[i].w*inc[i].w;
        }
        for (int o = 32; o > 0; o >>= 1) {
            s0 += __shfl_down(s0, o);
            s1 += __shfl_down(s1, o);
            s2 += __shfl_down(s2, o);
        }
        if (l == 0) { red[w][0] = s0; red[w][1] = s1; red[w][2] = s2; }
        __syncthreads();
        if (t == 0) {
            float r0 = 0.f, r1 = 0.f, r2 = 0.f;
            #pragma unroll
            for (int i = 0; i < 4; ++i) { r0 += red[i][0]; r1 += red[i][1]; r2 += red[i][2]; }
            float* o = part + ((size_t)(b*NN + n)*CH2 + ch)*3;
            o[0] = r0; o[1] = r1; o[2] = r2;
        }
        __syncthreads();
        #pragma unroll
        for (int i = 0; i < 4; ++i) { cur[i] = nxt[i]; nxt[i] = inc[i]; }
    }
}

// ---------------- Kernel 2: softmax -> combination coefficients ----------------
__global__ void k_coef(const float* __restrict__ part,
                       const float* __restrict__ pos_dec,
                       const float* __restrict__ len_dec,
                       float* __restrict__ coef) {
    int bn = threadIdx.x;
    if (bn >= BB*NN) return;
    int n = bn % NN;
    float d0 = 0.f, d1 = 0.f, d2 = 0.f;
    const float* p = part + (size_t)bn*CH2*3;
    for (int i = 0; i < CH2; ++i) { d0 += p[i*3]; d1 += p[i*3+1]; d2 += p[i*3+2]; }
    float pd = pos_dec[n], ld = len_dec[n];
    float l0 = (1.f - pd)*d0 + pd*d1;
    float l1 = ld*((1.f - pd)*d1 + pd*d2);
    float m  = fmaxf(l0, l1);
    float e0 = expf(l0 - m), e1 = expf(l1 - m);
    float inv = 1.f/(e0 + e1);
    float a0 = e0*inv, a1 = e1*inv;
    coef[bn*3+0] = a0*(1.f - pd);
    coef[bn*3+1] = a0*pd + a1*ld*(1.f - pd);
    coef[bn*3+2] = a1*ld*pd;
}

// ---------------- Kernel 3: conv_w fp32 -> bf16 ----------------
__global__ __launch_bounds__(256) void k_wconv(const float* __restrict__ w,
                                               ushort* __restrict__ wb) {
    int i = blockIdx.x*blockDim.x + threadIdx.x;
    size_t idx = (size_t)i*4;
    if (idx >= (size_t)NC*NC) return;
    float4 a = *(const float4*)(w + idx);
    ushort4 o;
    o.x = f2bf(a.x); o.y = f2bf(a.y); o.z = f2bf(a.z); o.w = f2bf(a.w);
    *(ushort4*)(wb + idx) = o;
}

// ---------------- Kernel 4: featT[b][hw][c] bf16 (transposed combo) ----------------
__global__ __launch_bounds__(256) void k_feat(const float* __restrict__ x,
                                              const float* __restrict__ coef,
                                              ushort* __restrict__ featT) {
    __shared__ float tile[32*129];
    int hwt = blockIdx.x;         // 0..71
    int n   = blockIdx.y;         // 0..9
    int b   = blockIdx.z;         // 0..15
    int bn  = b*NN + n;
    float c0 = coef[bn*3+0], c1 = coef[bn*3+1], c2 = coef[bn*3+2];
    int n1 = (n + 1) % NN, n2 = (n + 2) % NN;
    const float* p0 = x + ((size_t)b*NN + n )*DD;
    const float* p1 = x + ((size_t)b*NN + n1)*DD;
    const float* p2 = x + ((size_t)b*NN + n2)*DD;
    int t = threadIdx.x;
    int hw0 = hwt*32;

    int ccl = t >> 3;             // 0..31
    int hwi = (t & 7) * 4;        // 0..28
    #pragma unroll
    for (int p = 0; p < 4; ++p) {
        int cc = p*32 + ccl;
        size_t off = (size_t)cc*HWD + hw0 + hwi;
        float4 a = *(const float4*)(p0 + off);
        float4 u = *(const float4*)(p1 + off);
        float4 v = *(const float4*)(p2 + off);
        tile[(hwi+0)*129 + cc] = c0*a.x + c1*u.x + c2*v.x;
        tile[(hwi+1)*129 + cc] = c0*a.y + c1*u.y + c2*v.y;
        tile[(hwi+2)*129 + cc] = c0*a.z + c1*u.z + c2*v.z;
        tile[(hwi+3)*129 + cc] = c0*a.w + c1*u.w + c2*v.w;
    }
    __syncthreads();

    int hwl = t >> 4;             // 0..15
    int cc0 = (t & 15) * 8;       // 0..120
    #pragma unroll
    for (int p = 0; p < 2; ++p) {
        int hw = p*16 + hwl;
        const float* src = &tile[hw*129 + cc0];
        union { ushort us[8]; uint4 v; } pk;
        #pragma unroll
        for (int j = 0; j < 8; ++j) pk.us[j] = f2bf(src[j]);
        ushort* dst = featT + (size_t)b*HWD*NC + (size_t)(hw0 + hw)*NC + n*CC + cc0;
        *(uint4*)dst = pk.v;
    }
}

// ---------------- Kernel 5: m97-replica 128x128x32, 16 KiB LDS, 4 blocks/CU ----------------
// LDS per op: [128 rows][4 chunks of 16B], phys_chunk = c ^ ((row>>1)&3)
// (R2-verified zero-conflict involution). gload_lds dest linear, global source
// pre-swizzled. Single buffer, 2-sync loop; cross-block TLP (4 blocks/CU via
// launch_bounds(256,4)) hides the staging drain (m97/m114 mechanism).
__global__ __launch_bounds__(256, 4) void k_gemm(const ushort* __restrict__ Wb,
                                                 const ushort* __restrict__ featT,
                                                 const float* __restrict__ bias,
                                                 const float* __restrict__ x,
                                                 float* __restrict__ out) {
    __shared__ ushort As[BM*BK];   // 8 KiB
    __shared__ ushort Bs[BN*BK];   // 8 KiB

    // XCD-chunked mapping, o fastest: per XCD, W (3.3 MB) hot in L2,
    // featT panels (320 KB) get 10-block reuse.
    int bid = blockIdx.x;
    int wkid = (bid & 7) * 360 + (bid >> 3);   // 2880 = 8*360, bijective
    int b    = wkid / 180;
    int rem  = wkid % 180;
    int hwt  = rem / 10;
    int ot   = rem % 10;
    int o0 = ot*BM, hw0 = hwt*BN;

    int t = threadIdx.x;
    int l = t & 63;
    int w = t >> 6;
    int wr = w >> 1, wc = w & 1;      // 2x2 wave grid, 64x64 per wave

    const ushort* Ag = Wb + (size_t)o0*NC;
    const ushort* Bg = featT + (size_t)b*HWD*NC + (size_t)hw0*NC;

    // staging: 512 slots of 16B per op; thread t covers slots t and t+256
    int r0 = t >> 2, c0 = t & 3;
    size_t g0 = (size_t)r0*NC + (size_t)((c0 ^ ((r0 >> 1) & 3)) * 8);
    size_t g1 = g0 + (size_t)64*NC;   // row+64 has same swizzle bits

    // fragment read constants
    int fr = l & 15;
    int fc = l >> 4;                  // 0..3

    f32x4 acc[4][4] = {};

    for (int kt = 0; kt < TK; ++kt) {
        size_t k0 = (size_t)kt*BK;
        __syncthreads();              // all waves done reading previous tile
        gload_lds16(Ag + g0 + k0, As + t*8);
        gload_lds16(Ag + g1 + k0, As + (256 + t)*8);
        gload_lds16(Bg + g0 + k0, Bs + t*8);
        gload_lds16(Bg + g1 + k0, Bs + (256 + t)*8);
        __syncthreads();              // staging complete (vmcnt drained at barrier)

        bf16x8 afr[4], bfr[4];
        #pragma unroll
        for (int m = 0; m < 4; ++m) {
            int row = wr*64 + m*16 + fr;
            afr[m] = *(const bf16x8*)&As[row*BK + ((fc ^ ((row >> 1) & 3))*8)];
        }
        #pragma unroll
        for (int n = 0; n < 4; ++n) {
            int row = wc*64 + n*16 + fr;
            bfr[n] = *(const bf16x8*)&Bs[row*BK + ((fc ^ ((row >> 1) & 3))*8)];
        }
        #pragma unroll
        for (int m = 0; m < 4; ++m)
            #pragma unroll
            for (int n = 0; n < 4; ++n)
                acc[m][n] = __builtin_amdgcn_mfma_f32_16x16x32_bf16(afr[m], bfr[n], acc[m][n], 0, 0, 0);
    }

    // epilogue: + bias + residual x
    #pragma unroll
    for (int m = 0; m < 4; ++m) {
        int ro_base = o0 + wr*64 + m*16 + ((l >> 4) << 2);
        #pragma unroll
        for (int n = 0; n < 4; ++n) {
            int col = hw0 + wc*64 + n*16 + (l & 15);
            #pragma unroll
            for (int r = 0; r < 4; ++r) {
                int ro = ro_base + r;
                size_t idx = (size_t)b*NC*HWD + (size_t)ro*HWD + col;
                out[idx] = acc[m][n][r] + bias[ro] + x[idx];
            }
        }
    }
}

extern "C" void kernel_launch(void* const* d_in, const int* in_sizes, int n_in,
                              void* d_out, int out_size, void* d_ws, size_t ws_size,
                              hipStream_t stream) {
    const float* x       = (const float*)d_in[0];
    const float* pos_dec = (const float*)d_in[1];
    const float* len_dec = (const float*)d_in[2];
    const float* conv_w  = (const float*)d_in[3];
    const float* conv_b  = (const float*)d_in[4];
    float* out = (float*)d_out;

    char* ws = (char*)d_ws;
    ushort* featT = (ushort*)ws;                                   // 94,371,840 B
    ushort* wb    = (ushort*)(ws + FEAT_BYTES);                    // 3,276,800 B
    float*  part  = (float*)(ws + FEAT_BYTES + WB_BYTES);          // 138,240 B
    float*  coef  = part + PART_FLOATS;                            // 1,920 B

    k_dots <<<dim3(BB*CH2), 256, 0, stream>>>(x, part);
    k_coef <<<dim3(1), 256, 0, stream>>>(part, pos_dec, len_dec, coef);
    k_wconv<<<dim3(1600), 256, 0, stream>>>(conv_w, wb);
    k_feat <<<dim3(72, NN, BB), 256, 0, stream>>>(x, coef, featT);
    k_gemm <<<dim3(2880), 256, 0, stream>>>(wb, featT, conv_b, x, out);
}

// Round 8
// 314.507 us; speedup vs baseline: 1.0953x; 1.0017x over previous
//
#include <hip/hip_runtime.h>
#include <hip/hip_bf16.h>

#define BB 16
#define NN 10
#define CC 128
#define HWD 2304            // 48*48
#define DD (CC*HWD)         // 294912
#define NC (NN*CC)          // 1280

#define CH2 72              // chunks per b for dot kernel
#define CHUNK2 4096         // floats per chunk

#define BM 128
#define BN 128
#define BK 32
#define TK (NC/BK)          // 40 K-steps

typedef __bf16 bf16x8 __attribute__((ext_vector_type(8)));
typedef float  f32x4  __attribute__((ext_vector_type(4)));

#define FEAT_BYTES ((size_t)BB*HWD*NC*2)     // 94,371,840
#define WB_BYTES   ((size_t)NC*NC*2)         // 3,276,800
#define PART_FLOATS (BB*NN*CH2*3)            // 34,560

__device__ __forceinline__ ushort f2bf(float f) {
    __hip_bfloat16 h = __float2bfloat16(f);
    return *reinterpret_cast<ushort*>(&h);
}

__device__ __forceinline__ void gload_lds16(const ushort* g, ushort* l) {
    __builtin_amdgcn_global_load_lds(
        (const __attribute__((address_space(1))) void*)(const void*)g,
        (__attribute__((address_space(3))) void*)(void*)l,
        16, 0, 0);
}

// ---------------- Kernel 1: dots d0,d1,d2 — single pass over x ----------------
__global__ __launch_bounds__(256) void k_dots(const float* __restrict__ x,
                                              float* __restrict__ part) {
    int blk = blockIdx.x;             // 0..BB*CH2-1
    int ch = blk % CH2;
    int b  = blk / CH2;
    const float* base = x + (size_t)b*NN*DD + (size_t)ch*CHUNK2;
    int t = threadIdx.x;

    float4 cur[4], nxt[4], inc[4];
    #pragma unroll
    for (int i = 0; i < 4; ++i) cur[i] = *(const float4*)(base + (size_t)0*DD + i*1024 + t*4);
    #pragma unroll
    for (int i = 0; i < 4; ++i) nxt[i] = *(const float4*)(base + (size_t)1*DD + i*1024 + t*4);

    __shared__ float red[4][3];
    int w = t >> 6, l = t & 63;

    for (int n = 0; n < NN; ++n) {
        int n2 = (n + 2) % NN;
        #pragma unroll
        for (int i = 0; i < 4; ++i) inc[i] = *(const float4*)(base + (size_t)n2*DD + i*1024 + t*4);

        float s0 = 0.f, s1 = 0.f, s2 = 0.f;
        #pragma unroll
        for (int i = 0; i < 4; ++i) {
            s0 += cur[i].x*cur[i].x + cur[i].y*cur[i].y + cur[i].z*cur[i].z + cur[i].w*cur[i].w;
            s1 += cur[i].x*nxt[i].x + cur[i].y*nxt[i].y + cur[i].z*nxt[i].z + cur[i].w*nxt[i].w;
            s2 += cur[i].x*inc[i].x + cur[i].y*inc[i].y + cur[i].z*inc[i].z + cur[i].w*inc[i].w;
        }
        for (int o = 32; o > 0; o >>= 1) {
            s0 += __shfl_down(s0, o);
            s1 += __shfl_down(s1, o);
            s2 += __shfl_down(s2, o);
        }
        if (l == 0) { red[w][0] = s0; red[w][1] = s1; red[w][2] = s2; }
        __syncthreads();
        if (t == 0) {
            float r0 = 0.f, r1 = 0.f, r2 = 0.f;
            #pragma unroll
            for (int i = 0; i < 4; ++i) { r0 += red[i][0]; r1 += red[i][1]; r2 += red[i][2]; }
            float* o = part + ((size_t)(b*NN + n)*CH2 + ch)*3;
            o[0] = r0; o[1] = r1; o[2] = r2;
        }
        __syncthreads();
        #pragma unroll
        for (int i = 0; i < 4; ++i) { cur[i] = nxt[i]; nxt[i] = inc[i]; }
    }
}

// ---------------- Kernel 2: softmax -> combination coefficients ----------------
__global__ void k_coef(const float* __restrict__ part,
                       const float* __restrict__ pos_dec,
                       const float* __restrict__ len_dec,
                       float* __restrict__ coef) {
    int bn = threadIdx.x;
    if (bn >= BB*NN) return;
    int n = bn % NN;
    float d0 = 0.f, d1 = 0.f, d2 = 0.f;
    const float* p = part + (size_t)bn*CH2*3;
    for (int i = 0; i < CH2; ++i) { d0 += p[i*3]; d1 += p[i*3+1]; d2 += p[i*3+2]; }
    float pd = pos_dec[n], ld = len_dec[n];
    float l0 = (1.f - pd)*d0 + pd*d1;
    float l1 = ld*((1.f - pd)*d1 + pd*d2);
    float m  = fmaxf(l0, l1);
    float e0 = expf(l0 - m), e1 = expf(l1 - m);
    float inv = 1.f/(e0 + e1);
    float a0 = e0*inv, a1 = e1*inv;
    coef[bn*3+0] = a0*(1.f - pd);
    coef[bn*3+1] = a0*pd + a1*ld*(1.f - pd);
    coef[bn*3+2] = a1*ld*pd;
}

// ---------------- Kernel 3: conv_w fp32 -> bf16 ----------------
__global__ __launch_bounds__(256) void k_wconv(const float* __restrict__ w,
                                               ushort* __restrict__ wb) {
    int i = blockIdx.x*blockDim.x + threadIdx.x;
    size_t idx = (size_t)i*4;
    if (idx >= (size_t)NC*NC) return;
    float4 a = *(const float4*)(w + idx);
    ushort4 o;
    o.x = f2bf(a.x); o.y = f2bf(a.y); o.z = f2bf(a.z); o.w = f2bf(a.w);
    *(ushort4*)(wb + idx) = o;
}

// ---------------- Kernel 4: featT — single pass over n (x read ~1.2x) ----------------
// Block owns (b, hw-chunk of 32). Walks n keeping slices n,n+1,n+2 in registers
// (prefetching n+3), combos, transposes via LDS, writes featT[b][hw][n*CC+c] bf16.
__global__ __launch_bounds__(256) void k_feat(const float* __restrict__ x,
                                              const float* __restrict__ coef,
                                              ushort* __restrict__ featT) {
    __shared__ float tile[32*129];
    int hwt = blockIdx.x;         // 0..71
    int b   = blockIdx.y;         // 0..15
    int t = threadIdx.x;
    int hw0 = hwt*32;
    const float* xb = x + (size_t)b*NN*DD;

    int c_[4], ch_[4];
    size_t off_[4];
    #pragma unroll
    for (int i = 0; i < 4; ++i) {
        int s = i*256 + t;
        c_[i] = s >> 3; ch_[i] = s & 7;
        off_[i] = (size_t)c_[i]*HWD + hw0 + ch_[i]*4;
    }

    float4 s0[4], s1[4], s2[4], s3[4];
    #pragma unroll
    for (int i = 0; i < 4; ++i) s0[i] = *(const float4*)(xb + (size_t)0*DD + off_[i]);
    #pragma unroll
    for (int i = 0; i < 4; ++i) s1[i] = *(const float4*)(xb + (size_t)1*DD + off_[i]);
    #pragma unroll
    for (int i = 0; i < 4; ++i) s2[i] = *(const float4*)(xb + (size_t)2*DD + off_[i]);

    for (int n = 0; n < NN; ++n) {
        int n3 = (n + 3) % NN;
        #pragma unroll
        for (int i = 0; i < 4; ++i) s3[i] = *(const float4*)(xb + (size_t)n3*DD + off_[i]);

        int bn = b*NN + n;
        float c0 = coef[bn*3+0], c1 = coef[bn*3+1], c2 = coef[bn*3+2];

        #pragma unroll
        for (int i = 0; i < 4; ++i) {
            int hwb = ch_[i]*4, cc = c_[i];
            tile[(hwb+0)*129 + cc] = c0*s0[i].x + c1*s1[i].x + c2*s2[i].x;
            tile[(hwb+1)*129 + cc] = c0*s0[i].y + c1*s1[i].y + c2*s2[i].y;
            tile[(hwb+2)*129 + cc] = c0*s0[i].z + c1*s1[i].z + c2*s2[i].z;
            tile[(hwb+3)*129 + cc] = c0*s0[i].w + c1*s1[i].w + c2*s2[i].w;
        }
        __syncthreads();

        int hwl = t >> 4;             // 0..15
        int cc0 = (t & 15) * 8;       // 0..120
        #pragma unroll
        for (int p = 0; p < 2; ++p) {
            int hw = p*16 + hwl;
            const float* src = &tile[hw*129 + cc0];
            union { ushort us[8]; uint4 v; } pk;
            #pragma unroll
            for (int j = 0; j < 8; ++j) pk.us[j] = f2bf(src[j]);
            ushort* dst = featT + (size_t)b*HWD*NC + (size_t)(hw0 + hw)*NC + n*CC + cc0;
            *(uint4*)dst = pk.v;
        }
        __syncthreads();
        #pragma unroll
        for (int i = 0; i < 4; ++i) { s0[i] = s1[i]; s1[i] = s2[i]; s2[i] = s3[i]; }
    }
}

// ---------------- Kernel 5: 128x128x32 GEMM, dbuf, issue-early / drain-late ----------------
// T3 minimum-2-phase recipe: STAGE(next) -> ds_read+MFMA(cur) -> __syncthreads
// (single vmcnt(0) drain per K-step, AFTER compute). 32 KiB LDS -> 4 blocks/CU.
// Zero-conflict chunk swizzle phys = c ^ ((row>>1)&3); gload dest linear,
// global source pre-swizzled.
__global__ __launch_bounds__(256, 4) void k_gemm(const ushort* __restrict__ Wb,
                                                 const ushort* __restrict__ featT,
                                                 const float* __restrict__ bias,
                                                 const float* __restrict__ x,
                                                 float* __restrict__ out) {
    __shared__ ushort As[2][BM*BK];   // 2 x 8 KiB
    __shared__ ushort Bs[2][BN*BK];   // 2 x 8 KiB

    // XCD-chunked mapping, o fastest: per XCD, W (3.3 MB) hot in L2,
    // featT panels (320 KB) get 10-block reuse.
    int bid = blockIdx.x;
    int wkid = (bid & 7) * 360 + (bid >> 3);   // 2880 = 8*360, bijective
    int b    = wkid / 180;
    int rem  = wkid % 180;
    int hwt  = rem / 10;
    int ot   = rem % 10;
    int o0 = ot*BM, hw0 = hwt*BN;

    int t = threadIdx.x;
    int l = t & 63;
    int w = t >> 6;
    int wr = w >> 1, wc = w & 1;      // 2x2 wave grid, 64x64 per wave

    const ushort* Ag = Wb + (size_t)o0*NC;
    const ushort* Bg = featT + (size_t)b*HWD*NC + (size_t)hw0*NC;

    // staging: 512 slots of 16B per op; thread t covers slots t and t+256
    int r0 = t >> 2, c0 = t & 3;
    size_t g0 = (size_t)r0*NC + (size_t)((c0 ^ ((r0 >> 1) & 3)) * 8);
    size_t g1 = g0 + (size_t)64*NC;   // row+64 has same swizzle bits

#define STAGE(buf_, kt_) do { \
    size_t k0_ = (size_t)(kt_)*BK; \
    ushort* da_ = &As[buf_][0]; \
    ushort* db_ = &Bs[buf_][0]; \
    gload_lds16(Ag + g0 + k0_, da_ + t*8); \
    gload_lds16(Ag + g1 + k0_, da_ + (256 + t)*8); \
    gload_lds16(Bg + g0 + k0_, db_ + t*8); \
    gload_lds16(Bg + g1 + k0_, db_ + (256 + t)*8); \
} while (0)

    // fragment read constants
    int fr = l & 15;
    int fc = l >> 4;                  // 0..3

    f32x4 acc[4][4] = {};

    STAGE(0, 0);
    __syncthreads();                  // prologue drain

    for (int kt = 0; kt < TK; ++kt) {
        int buf = kt & 1;
        if (kt + 1 < TK) STAGE(buf ^ 1, kt + 1);   // issue early
        __builtin_amdgcn_sched_barrier(0);         // keep issue above compute

        const ushort* as = &As[buf][0];
        const ushort* bs = &Bs[buf][0];

        bf16x8 afr[4], bfr[4];
        #pragma unroll
        for (int m = 0; m < 4; ++m) {
            int row = wr*64 + m*16 + fr;
            afr[m] = *(const bf16x8*)&as[row*BK + ((fc ^ ((row >> 1) & 3))*8)];
        }
        #pragma unroll
        for (int n = 0; n < 4; ++n) {
            int row = wc*64 + n*16 + fr;
            bfr[n] = *(const bf16x8*)&bs[row*BK + ((fc ^ ((row >> 1) & 3))*8)];
        }
        #pragma unroll
        for (int m = 0; m < 4; ++m)
            #pragma unroll
            for (int n = 0; n < 4; ++n)
                acc[m][n] = __builtin_amdgcn_mfma_f32_16x16x32_bf16(afr[m], bfr[n], acc[m][n], 0, 0, 0);

        __syncthreads();              // single drain per K-step, AFTER compute
    }
#undef STAGE

    // epilogue: + bias + residual x
    #pragma unroll
    for (int m = 0; m < 4; ++m) {
        int ro_base = o0 + wr*64 + m*16 + ((l >> 4) << 2);
        #pragma unroll
        for (int n = 0; n < 4; ++n) {
            int col = hw0 + wc*64 + n*16 + (l & 15);
            #pragma unroll
            for (int r = 0; r < 4; ++r) {
                int ro = ro_base + r;
                size_t idx = (size_t)b*NC*HWD + (size_t)ro*HWD + col;
                out[idx] = acc[m][n][r] + bias[ro] + x[idx];
            }
        }
    }
}

extern "C" void kernel_launch(void* const* d_in, const int* in_sizes, int n_in,
                              void* d_out, int out_size, void* d_ws, size_t ws_size,
                              hipStream_t stream) {
    const float* x       = (const float*)d_in[0];
    const float* pos_dec = (const float*)d_in[1];
    const float* len_dec = (const float*)d_in[2];
    const float* conv_w  = (const float*)d_in[3];
    const float* conv_b  = (const float*)d_in[4];
    float* out = (float*)d_out;

    char* ws = (char*)d_ws;
    ushort* featT = (ushort*)ws;                                   // 94,371,840 B
    ushort* wb    = (ushort*)(ws + FEAT_BYTES);                    // 3,276,800 B
    float*  part  = (float*)(ws + FEAT_BYTES + WB_BYTES);         // 138,240 B
    float*  coef  = part + PART_FLOATS;                            // 1,920 B

    k_dots <<<dim3(BB*CH2), 256, 0, stream>>>(x, part);
    k_coef <<<dim3(1), 256, 0, stream>>>(part, pos_dec, len_dec, coef);
    k_wconv<<<dim3(1600), 256, 0, stream>>>(conv_w, wb);
    k_feat <<<dim3(72, BB), 256, 0, stream>>>(x, coef, featT);
    k_gemm <<<dim3(2880), 256, 0, stream>>>(wb, featT, conv_b, x, out);
}

// Round 9
// 305.762 us; speedup vs baseline: 1.1267x; 1.0286x over previous
//
#include <hip/hip_runtime.h>
#include <hip/hip_bf16.h>

#define BB 16
#define NN 10
#define CC 128
#define HWD 2304            // 48*48
#define DD (CC*HWD)         // 294912
#define NC (NN*CC)          // 1280

#define CH2 72              // chunks per b for dot kernel
#define CHUNK2 4096         // floats per chunk

#define BM 256
#define BN 128
#define BK 32
#define TK (NC/BK)          // 40 K-steps

typedef __bf16 bf16x8 __attribute__((ext_vector_type(8)));
typedef float  f32x4  __attribute__((ext_vector_type(4)));

#define FEAT_BYTES ((size_t)BB*HWD*NC*2)     // 94,371,840
#define WB_BYTES   ((size_t)NC*NC*2)         // 3,276,800
#define PART_FLOATS (BB*NN*CH2*3)            // 34,560

__device__ __forceinline__ ushort f2bf(float f) {
    __hip_bfloat16 h = __float2bfloat16(f);
    return *reinterpret_cast<ushort*>(&h);
}

__device__ __forceinline__ void gload_lds16(const ushort* g, ushort* l) {
    __builtin_amdgcn_global_load_lds(
        (const __attribute__((address_space(1))) void*)(const void*)g,
        (__attribute__((address_space(3))) void*)(void*)l,
        16, 0, 0);
}

// ---------------- Kernel 1: dots d0,d1,d2 — single pass over x ----------------
__global__ __launch_bounds__(256) void k_dots(const float* __restrict__ x,
                                              float* __restrict__ part) {
    int blk = blockIdx.x;             // 0..BB*CH2-1
    int ch = blk % CH2;
    int b  = blk / CH2;
    const float* base = x + (size_t)b*NN*DD + (size_t)ch*CHUNK2;
    int t = threadIdx.x;

    float4 cur[4], nxt[4], inc[4];
    #pragma unroll
    for (int i = 0; i < 4; ++i) cur[i] = *(const float4*)(base + (size_t)0*DD + i*1024 + t*4);
    #pragma unroll
    for (int i = 0; i < 4; ++i) nxt[i] = *(const float4*)(base + (size_t)1*DD + i*1024 + t*4);

    __shared__ float red[4][3];
    int w = t >> 6, l = t & 63;

    for (int n = 0; n < NN; ++n) {
        int n2 = (n + 2) % NN;
        #pragma unroll
        for (int i = 0; i < 4; ++i) inc[i] = *(const float4*)(base + (size_t)n2*DD + i*1024 + t*4);

        float s0 = 0.f, s1 = 0.f, s2 = 0.f;
        #pragma unroll
        for (int i = 0; i < 4; ++i) {
            s0 += cur[i].x*cur[i].x + cur[i].y*cur[i].y + cur[i].z*cur[i].z + cur[i].w*cur[i].w;
            s1 += cur[i].x*nxt[i].x + cur[i].y*nxt[i].y + cur[i].z*nxt[i].z + cur[i].w*nxt[i].w;
            s2 += cur[i].x*inc[i].x + cur[i].y*inc[i].y + cur[i].z*inc[i].z + cur[i].w*inc[i].w;
        }
        for (int o = 32; o > 0; o >>= 1) {
            s0 += __shfl_down(s0, o);
            s1 += __shfl_down(s1, o);
            s2 += __shfl_down(s2, o);
        }
        if (l == 0) { red[w][0] = s0; red[w][1] = s1; red[w][2] = s2; }
        __syncthreads();
        if (t == 0) {
            float r0 = 0.f, r1 = 0.f, r2 = 0.f;
            #pragma unroll
            for (int i = 0; i < 4; ++i) { r0 += red[i][0]; r1 += red[i][1]; r2 += red[i][2]; }
            float* o = part + ((size_t)(b*NN + n)*CH2 + ch)*3;
            o[0] = r0; o[1] = r1; o[2] = r2;
        }
        __syncthreads();
        #pragma unroll
        for (int i = 0; i < 4; ++i) { cur[i] = nxt[i]; nxt[i] = inc[i]; }
    }
}

// ---------------- Kernel 2: softmax -> combination coefficients ----------------
__global__ void k_coef(const float* __restrict__ part,
                       const float* __restrict__ pos_dec,
                       const float* __restrict__ len_dec,
                       float* __restrict__ coef) {
    int bn = threadIdx.x;
    if (bn >= BB*NN) return;
    int n = bn % NN;
    float d0 = 0.f, d1 = 0.f, d2 = 0.f;
    const float* p = part + (size_t)bn*CH2*3;
    for (int i = 0; i < CH2; ++i) { d0 += p[i*3]; d1 += p[i*3+1]; d2 += p[i*3+2]; }
    float pd = pos_dec[n], ld = len_dec[n];
    float l0 = (1.f - pd)*d0 + pd*d1;
    float l1 = ld*((1.f - pd)*d1 + pd*d2);
    float m  = fmaxf(l0, l1);
    float e0 = expf(l0 - m), e1 = expf(l1 - m);
    float inv = 1.f/(e0 + e1);
    float a0 = e0*inv, a1 = e1*inv;
    coef[bn*3+0] = a0*(1.f - pd);
    coef[bn*3+1] = a0*pd + a1*ld*(1.f - pd);
    coef[bn*3+2] = a1*ld*pd;
}

// ---------------- Kernel 3: conv_w fp32 -> bf16 ----------------
__global__ __launch_bounds__(256) void k_wconv(const float* __restrict__ w,
                                               ushort* __restrict__ wb) {
    int i = blockIdx.x*blockDim.x + threadIdx.x;
    size_t idx = (size_t)i*4;
    if (idx >= (size_t)NC*NC) return;
    float4 a = *(const float4*)(w + idx);
    ushort4 o;
    o.x = f2bf(a.x); o.y = f2bf(a.y); o.z = f2bf(a.z); o.w = f2bf(a.w);
    *(ushort4*)(wb + idx) = o;
}

// ---------------- Kernel 4: featT — single pass over n (x read ~1.2x) ----------------
__global__ __launch_bounds__(256) void k_feat(const float* __restrict__ x,
                                              const float* __restrict__ coef,
                                              ushort* __restrict__ featT) {
    __shared__ float tile[32*129];
    int hwt = blockIdx.x;         // 0..71
    int b   = blockIdx.y;         // 0..15
    int t = threadIdx.x;
    int hw0 = hwt*32;
    const float* xb = x + (size_t)b*NN*DD;

    int c_[4], ch_[4];
    size_t off_[4];
    #pragma unroll
    for (int i = 0; i < 4; ++i) {
        int s = i*256 + t;
        c_[i] = s >> 3; ch_[i] = s & 7;
        off_[i] = (size_t)c_[i]*HWD + hw0 + ch_[i]*4;
    }

    float4 s0[4], s1[4], s2[4], s3[4];
    #pragma unroll
    for (int i = 0; i < 4; ++i) s0[i] = *(const float4*)(xb + (size_t)0*DD + off_[i]);
    #pragma unroll
    for (int i = 0; i < 4; ++i) s1[i] = *(const float4*)(xb + (size_t)1*DD + off_[i]);
    #pragma unroll
    for (int i = 0; i < 4; ++i) s2[i] = *(const float4*)(xb + (size_t)2*DD + off_[i]);

    for (int n = 0; n < NN; ++n) {
        int n3 = (n + 3) % NN;
        #pragma unroll
        for (int i = 0; i < 4; ++i) s3[i] = *(const float4*)(xb + (size_t)n3*DD + off_[i]);

        int bn = b*NN + n;
        float c0 = coef[bn*3+0], c1 = coef[bn*3+1], c2 = coef[bn*3+2];

        #pragma unroll
        for (int i = 0; i < 4; ++i) {
            int hwb = ch_[i]*4, cc = c_[i];
            tile[(hwb+0)*129 + cc] = c0*s0[i].x + c1*s1[i].x + c2*s2[i].x;
            tile[(hwb+1)*129 + cc] = c0*s0[i].y + c1*s1[i].y + c2*s2[i].y;
            tile[(hwb+2)*129 + cc] = c0*s0[i].z + c1*s1[i].z + c2*s2[i].z;
            tile[(hwb+3)*129 + cc] = c0*s0[i].w + c1*s1[i].w + c2*s2[i].w;
        }
        __syncthreads();

        int hwl = t >> 4;             // 0..15
        int cc0 = (t & 15) * 8;       // 0..120
        #pragma unroll
        for (int p = 0; p < 2; ++p) {
            int hw = p*16 + hwl;
            const float* src = &tile[hw*129 + cc0];
            union { ushort us[8]; uint4 v; } pk;
            #pragma unroll
            for (int j = 0; j < 8; ++j) pk.us[j] = f2bf(src[j]);
            ushort* dst = featT + (size_t)b*HWD*NC + (size_t)(hw0 + hw)*NC + n*CC + cc0;
            *(uint4*)dst = pk.v;
        }
        __syncthreads();
        #pragma unroll
        for (int i = 0; i < 4; ++i) { s0[i] = s1[i]; s1[i] = s2[i]; s2[i] = s3[i]; }
    }
}

// ---------------- Kernel 5: 256x128x32 GEMM, dbuf, issue-early / drain-late ----------------
// BM=256 halves featT(L3) re-reads: B panel read 5x instead of 10x.
// 8 waves (4M x 2N), 64x64 per wave, acc[4][4]; LDS 48 KiB -> 2 blocks/CU
// (16 waves/CU, same as R8). Zero-conflict chunk swizzle phys = c ^ ((row>>1)&3);
// gload dest linear, global source pre-swizzled. Single vmcnt(0) drain per
// K-step at the barrier, AFTER compute.
__global__ __launch_bounds__(512, 4) void k_gemm(const ushort* __restrict__ Wb,
                                                 const ushort* __restrict__ featT,
                                                 const float* __restrict__ bias,
                                                 const float* __restrict__ x,
                                                 float* __restrict__ out) {
    __shared__ ushort As[2][BM*BK];   // 2 x 16 KiB
    __shared__ ushort Bs[2][BN*BK];   // 2 x 8 KiB

    // XCD-chunked mapping, o fastest: per XCD, W (3.3 MB) hot in L2,
    // featT panels (320 KB) get 5-block consecutive reuse.
    int bid = blockIdx.x;
    int wkid = (bid & 7) * 180 + (bid >> 3);   // 1440 = 8*180, bijective
    int b    = wkid / 90;
    int rem  = wkid % 90;
    int hwt  = rem / 5;    // 0..17
    int ot   = rem % 5;    // 0..4
    int o0 = ot*BM, hw0 = hwt*BN;

    int t = threadIdx.x;
    int l = t & 63;
    int w = t >> 6;
    int wr = w >> 1, wc = w & 1;      // 4x2 wave grid, 64x64 per wave

    const ushort* Ag = Wb + (size_t)o0*NC;
    const ushort* Bg = featT + (size_t)b*HWD*NC + (size_t)hw0*NC;

    // staging: A = 1024 slots of 16B (thread t -> slots t, t+512); B = 512 slots.
    // slot s: row = s>>2, chunk = s&3; rows s and s+512 share swizzle bits.
    int r0 = t >> 2, c0 = t & 3;
    size_t g0 = (size_t)r0*NC + (size_t)((c0 ^ ((r0 >> 1) & 3)) * 8);

#define STAGE(buf_, kt_) do { \
    size_t k0_ = (size_t)(kt_)*BK; \
    ushort* da_ = &As[buf_][0]; \
    ushort* db_ = &Bs[buf_][0]; \
    gload_lds16(Ag + g0 + k0_,                  da_ + t*8); \
    gload_lds16(Ag + g0 + (size_t)128*NC + k0_, da_ + (512 + t)*8); \
    gload_lds16(Bg + g0 + k0_,                  db_ + t*8); \
} while (0)

    // fragment read constants
    int fr = l & 15;
    int fc = l >> 4;                  // 0..3

    f32x4 acc[4][4] = {};

    STAGE(0, 0);
    __syncthreads();                  // prologue drain

    for (int kt = 0; kt < TK; ++kt) {
        int buf = kt & 1;
        if (kt + 1 < TK) STAGE(buf ^ 1, kt + 1);   // issue early
        __builtin_amdgcn_sched_barrier(0);         // keep issue above compute

        const ushort* as = &As[buf][0];
        const ushort* bs = &Bs[buf][0];

        bf16x8 afr[4], bfr[4];
        #pragma unroll
        for (int m = 0; m < 4; ++m) {
            int row = wr*64 + m*16 + fr;
            afr[m] = *(const bf16x8*)&as[row*BK + ((fc ^ ((row >> 1) & 3))*8)];
        }
        #pragma unroll
        for (int n = 0; n < 4; ++n) {
            int row = wc*64 + n*16 + fr;
            bfr[n] = *(const bf16x8*)&bs[row*BK + ((fc ^ ((row >> 1) & 3))*8)];
        }
        #pragma unroll
        for (int m = 0; m < 4; ++m)
            #pragma unroll
            for (int n = 0; n < 4; ++n)
                acc[m][n] = __builtin_amdgcn_mfma_f32_16x16x32_bf16(afr[m], bfr[n], acc[m][n], 0, 0, 0);

        __syncthreads();              // single drain per K-step, AFTER compute
    }
#undef STAGE

    // epilogue: + bias + residual x
    #pragma unroll
    for (int m = 0; m < 4; ++m) {
        int ro_base = o0 + wr*64 + m*16 + ((l >> 4) << 2);
        #pragma unroll
        for (int n = 0; n < 4; ++n) {
            int col = hw0 + wc*64 + n*16 + (l & 15);
            #pragma unroll
            for (int r = 0; r < 4; ++r) {
                int ro = ro_base + r;
                size_t idx = (size_t)b*NC*HWD + (size_t)ro*HWD + col;
                out[idx] = acc[m][n][r] + bias[ro] + x[idx];
            }
        }
    }
}

extern "C" void kernel_launch(void* const* d_in, const int* in_sizes, int n_in,
                              void* d_out, int out_size, void* d_ws, size_t ws_size,
                              hipStream_t stream) {
    const float* x       = (const float*)d_in[0];
    const float* pos_dec = (const float*)d_in[1];
    const float* len_dec = (const float*)d_in[2];
    const float* conv_w  = (const float*)d_in[3];
    const float* conv_b  = (const float*)d_in[4];
    float* out = (float*)d_out;

    char* ws = (char*)d_ws;
    ushort* featT = (ushort*)ws;                                   // 94,371,840 B
    ushort* wb    = (ushort*)(ws + FEAT_BYTES);                    // 3,276,800 B
    float*  part  = (float*)(ws + FEAT_BYTES + WB_BYTES);          // 138,240 B
    float*  coef  = part + PART_FLOATS;                            // 1,920 B

    k_dots <<<dim3(BB*CH2), 256, 0, stream>>>(x, part);
    k_coef <<<dim3(1), 256, 0, stream>>>(part, pos_dec, len_dec, coef);
    k_wconv<<<dim3(1600), 256, 0, stream>>>(conv_w, wb);
    k_feat <<<dim3(72, BB), 256, 0, stream>>>(x, coef, featT);
    k_gemm <<<dim3(1440), 512, 0, stream>>>(wb, featT, conv_b, x, out);
}

// Round 10
// 300.206 us; speedup vs baseline: 1.1475x; 1.0185x over previous
//
#include <hip/hip_runtime.h>
#include <hip/hip_bf16.h>

#define BB 16
#define NN 10
#define CC 128
#define HWD 2304            // 48*48
#define DD (CC*HWD)         // 294912
#define NC (NN*CC)          // 1280

#define CH2 72              // chunks per b for dot kernel
#define CHUNK2 4096         // floats per chunk

#define BM 256
#define BN 256
#define BK 64
#define TK (NC/BK)          // 20 K-tiles

typedef __bf16 bf16x8 __attribute__((ext_vector_type(8)));
typedef float  f32x4  __attribute__((ext_vector_type(4)));

#define FEAT_BYTES ((size_t)BB*HWD*NC*2)     // 94,371,840
#define WB_BYTES   ((size_t)NC*NC*2)         // 3,276,800
#define PART_FLOATS (BB*NN*CH2*3)            // 34,560

__device__ __forceinline__ ushort f2bf(float f) {
    __hip_bfloat16 h = __float2bfloat16(f);
    return *reinterpret_cast<ushort*>(&h);
}

__device__ __forceinline__ void gload_lds16(const ushort* g, ushort* l) {
    __builtin_amdgcn_global_load_lds(
        (const __attribute__((address_space(1))) void*)(const void*)g,
        (__attribute__((address_space(3))) void*)(void*)l,
        16, 0, 0);
}

// ---------------- Kernel 1: dots d0,d1,d2 — single pass over x ----------------
__global__ __launch_bounds__(256) void k_dots(const float* __restrict__ x,
                                              float* __restrict__ part) {
    int blk = blockIdx.x;             // 0..BB*CH2-1
    int ch = blk % CH2;
    int b  = blk / CH2;
    const float* base = x + (size_t)b*NN*DD + (size_t)ch*CHUNK2;
    int t = threadIdx.x;

    float4 cur[4], nxt[4], inc[4];
    #pragma unroll
    for (int i = 0; i < 4; ++i) cur[i] = *(const float4*)(base + (size_t)0*DD + i*1024 + t*4);
    #pragma unroll
    for (int i = 0; i < 4; ++i) nxt[i] = *(const float4*)(base + (size_t)1*DD + i*1024 + t*4);

    __shared__ float red[4][3];
    int w = t >> 6, l = t & 63;

    for (int n = 0; n < NN; ++n) {
        int n2 = (n + 2) % NN;
        #pragma unroll
        for (int i = 0; i < 4; ++i) inc[i] = *(const float4*)(base + (size_t)n2*DD + i*1024 + t*4);

        float s0 = 0.f, s1 = 0.f, s2 = 0.f;
        #pragma unroll
        for (int i = 0; i < 4; ++i) {
            s0 += cur[i].x*cur[i].x + cur[i].y*cur[i].y + cur[i].z*cur[i].z + cur[i].w*cur[i].w;
            s1 += cur[i].x*nxt[i].x + cur[i].y*nxt[i].y + cur[i].z*nxt[i].z + cur[i].w*nxt[i].w;
            s2 += cur[i].x*inc[i].x + cur[i].y*inc[i].y + cur[i].z*inc[i].z + cur[i].w*inc[i].w;
        }
        for (int o = 32; o > 0; o >>= 1) {
            s0 += __shfl_down(s0, o);
            s1 += __shfl_down(s1, o);
            s2 += __shfl_down(s2, o);
        }
        if (l == 0) { red[w][0] = s0; red[w][1] = s1; red[w][2] = s2; }
        __syncthreads();
        if (t == 0) {
            float r0 = 0.f, r1 = 0.f, r2 = 0.f;
            #pragma unroll
            for (int i = 0; i < 4; ++i) { r0 += red[i][0]; r1 += red[i][1]; r2 += red[i][2]; }
            float* o = part + ((size_t)(b*NN + n)*CH2 + ch)*3;
            o[0] = r0; o[1] = r1; o[2] = r2;
        }
        __syncthreads();
        #pragma unroll
        for (int i = 0; i < 4; ++i) { cur[i] = nxt[i]; nxt[i] = inc[i]; }
    }
}

// ---------------- Kernel 2: softmax -> combination coefficients ----------------
__global__ void k_coef(const float* __restrict__ part,
                       const float* __restrict__ pos_dec,
                       const float* __restrict__ len_dec,
                       float* __restrict__ coef) {
    int bn = threadIdx.x;
    if (bn >= BB*NN) return;
    int n = bn % NN;
    float d0 = 0.f, d1 = 0.f, d2 = 0.f;
    const float* p = part + (size_t)bn*CH2*3;
    for (int i = 0; i < CH2; ++i) { d0 += p[i*3]; d1 += p[i*3+1]; d2 += p[i*3+2]; }
    float pd = pos_dec[n], ld = len_dec[n];
    float l0 = (1.f - pd)*d0 + pd*d1;
    float l1 = ld*((1.f - pd)*d1 + pd*d2);
    float m  = fmaxf(l0, l1);
    float e0 = expf(l0 - m), e1 = expf(l1 - m);
    float inv = 1.f/(e0 + e1);
    float a0 = e0*inv, a1 = e1*inv;
    coef[bn*3+0] = a0*(1.f - pd);
    coef[bn*3+1] = a0*pd + a1*ld*(1.f - pd);
    coef[bn*3+2] = a1*ld*pd;
}

// ---------------- Kernel 3: conv_w fp32 -> bf16 ----------------
__global__ __launch_bounds__(256) void k_wconv(const float* __restrict__ w,
                                               ushort* __restrict__ wb) {
    int i = blockIdx.x*blockDim.x + threadIdx.x;
    size_t idx = (size_t)i*4;
    if (idx >= (size_t)NC*NC) return;
    float4 a = *(const float4*)(w + idx);
    ushort4 o;
    o.x = f2bf(a.x); o.y = f2bf(a.y); o.z = f2bf(a.z); o.w = f2bf(a.w);
    *(ushort4*)(wb + idx) = o;
}

// ---------------- Kernel 4: featT — single pass over n (x read ~1.2x) ----------------
__global__ __launch_bounds__(256) void k_feat(const float* __restrict__ x,
                                              const float* __restrict__ coef,
                                              ushort* __restrict__ featT) {
    __shared__ float tile[32*129];
    int hwt = blockIdx.x;         // 0..71
    int b   = blockIdx.y;         // 0..15
    int t = threadIdx.x;
    int hw0 = hwt*32;
    const float* xb = x + (size_t)b*NN*DD;

    int c_[4], ch_[4];
    size_t off_[4];
    #pragma unroll
    for (int i = 0; i < 4; ++i) {
        int s = i*256 + t;
        c_[i] = s >> 3; ch_[i] = s & 7;
        off_[i] = (size_t)c_[i]*HWD + hw0 + ch_[i]*4;
    }

    float4 s0[4], s1[4], s2[4], s3[4];
    #pragma unroll
    for (int i = 0; i < 4; ++i) s0[i] = *(const float4*)(xb + (size_t)0*DD + off_[i]);
    #pragma unroll
    for (int i = 0; i < 4; ++i) s1[i] = *(const float4*)(xb + (size_t)1*DD + off_[i]);
    #pragma unroll
    for (int i = 0; i < 4; ++i) s2[i] = *(const float4*)(xb + (size_t)2*DD + off_[i]);

    for (int n = 0; n < NN; ++n) {
        int n3 = (n + 3) % NN;
        #pragma unroll
        for (int i = 0; i < 4; ++i) s3[i] = *(const float4*)(xb + (size_t)n3*DD + off_[i]);

        int bn = b*NN + n;
        float c0 = coef[bn*3+0], c1 = coef[bn*3+1], c2 = coef[bn*3+2];

        #pragma unroll
        for (int i = 0; i < 4; ++i) {
            int hwb = ch_[i]*4, cc = c_[i];
            tile[(hwb+0)*129 + cc] = c0*s0[i].x + c1*s1[i].x + c2*s2[i].x;
            tile[(hwb+1)*129 + cc] = c0*s0[i].y + c1*s1[i].y + c2*s2[i].y;
            tile[(hwb+2)*129 + cc] = c0*s0[i].z + c1*s1[i].z + c2*s2[i].z;
            tile[(hwb+3)*129 + cc] = c0*s0[i].w + c1*s1[i].w + c2*s2[i].w;
        }
        __syncthreads();

        int hwl = t >> 4;             // 0..15
        int cc0 = (t & 15) * 8;       // 0..120
        #pragma unroll
        for (int p = 0; p < 2; ++p) {
            int hw = p*16 + hwl;
            const float* src = &tile[hw*129 + cc0];
            union { ushort us[8]; uint4 v; } pk;
            #pragma unroll
            for (int j = 0; j < 8; ++j) pk.us[j] = f2bf(src[j]);
            ushort* dst = featT + (size_t)b*HWD*NC + (size_t)(hw0 + hw)*NC + n*CC + cc0;
            *(uint4*)dst = pk.v;
        }
        __syncthreads();
        #pragma unroll
        for (int i = 0; i < 4; ++i) { s0[i] = s1[i]; s1[i] = s2[i]; s2[i] = s3[i]; }
    }
}

// ---------------- Kernel 5: 256x256x64, 4-phase/K-tile, BRANCH-FREE counted vmcnt ----------------
// Regions per buf: 0=Aklo 1=Akhi 2=Bklo 3=Bkhi, each [256 rows][32 k] ushort (16 KiB).
// phys_chunk = c ^ ((row>>1)&3) (R2-verified zero-conflict). gload dest linear,
// global source pre-swizzled. Phases consume K-halves:
//   ph1 (klo, n01): reads A-klo frags(8) + B-klo n01(2); stages Aklo(kt+1)
//   ph2 (klo, n23): reads B-klo n23(2);                  stages Bklo(kt+1); vmcnt(4)
//   ph3 (khi, n01): reads A-khi frags(8) + B-khi n01(2); stages Akhi(kt+1)
//   ph4 (khi, n23): reads B-khi n23(2);                  stages Bkhi(kt+1); vmcnt(4)
// Queue at each wait = 8 loads; vmcnt(4) drains the 4 oldest (the K-half needed
// 1 phase later). Steady loop kt=0..TK-2 is branch-free; last tile peeled.
#define BAR()   __builtin_amdgcn_s_barrier()
#define SB()    __builtin_amdgcn_sched_barrier(0)
#define LGKM0() asm volatile("s_waitcnt lgkmcnt(0)" ::: "memory")
#define VM(N)   asm volatile("s_waitcnt vmcnt(" #N ")" ::: "memory")

__global__ __launch_bounds__(512, 2) void k_gemm(const ushort* __restrict__ Wb,
                                                 const ushort* __restrict__ featT,
                                                 const float* __restrict__ bias,
                                                 const float* __restrict__ x,
                                                 float* __restrict__ out) {
    __shared__ ushort L[2][4][BM*32];   // 2 bufs x 4 regions x 16 KiB = 128 KiB

    int bid = blockIdx.x;
    int wkid = (bid & 7) * 90 + (bid >> 3);   // bijective XCD swizzle (720 = 8*90)
    int b   = wkid / 45;
    int r45 = wkid % 45;
    int hwt = r45 / 5;
    int ot  = r45 % 5;
    int o0 = ot*BM, hw0 = hwt*BN;

    int t = threadIdx.x;
    int l = t & 63;
    int w = t >> 6;
    int wr = w >> 2, wc = w & 3;      // 2(M) x 4(N) waves; wave tile 128x64

    const ushort* Ag = Wb + (size_t)o0*NC;
    const ushort* Bg = featT + (size_t)b*HWD*NC + (size_t)hw0*NC;

    // staging: region = 1024 slots of 16B; thread t covers slots t and t+512
    int r0 = t >> 2, c0 = t & 3;      // rows 0..127 ; rows+128 share swizzle bits
    size_t g0 = (size_t)r0*NC + (size_t)((c0 ^ ((r0 >> 1) & 3)) * 8);
    size_t g1 = g0 + (size_t)128*NC;

#define STAGE(nb_, reg_, gp_) do { \
    gload_lds16((gp_) + g0, &L[nb_][reg_][t*8]); \
    gload_lds16((gp_) + g1, &L[nb_][reg_][(512 + t)*8]); } while (0)

    // fragment read constants (swizzle chunk identical for all frags)
    int fr = l & 15;
    int kc = ((l >> 4) ^ ((l >> 1) & 3)) * 8;
    int rowA = (wr*128 + fr)*32 + kc;     // + i*512
    int rowB = (wc*64  + fr)*32 + kc;     // + n*512

    f32x4 acc[8][4] = {};
    bf16x8 af[8], bfA, bfB;

    // ---- prologue: stage tile 0 (klo first), wait klo ----
    STAGE(0, 0, Ag);                 // Aklo(0)
    STAGE(0, 2, Bg);                 // Bklo(0)
    STAGE(0, 1, Ag + 32);            // Akhi(0)
    STAGE(0, 3, Bg + 32);            // Bkhi(0)
    VM(4);                           // klo(0) done; khi(0) in flight
    BAR(); SB();

    for (int kt = 0; kt < TK - 1; ++kt) {
        int buf = kt & 1, nbuf = buf ^ 1;
        const ushort* A0 = &L[buf][0][0];
        const ushort* A1 = &L[buf][1][0];
        const ushort* B0 = &L[buf][2][0];
        const ushort* B1 = &L[buf][3][0];
        const ushort* Agk = Ag + (size_t)(kt + 1)*BK;
        const ushort* Bgk = Bg + (size_t)(kt + 1)*BK;

        // ---- ph1: klo, n01 ----
        #pragma unroll
        for (int i = 0; i < 8; ++i) af[i] = *(const bf16x8*)&A0[rowA + i*512];
        bfA = *(const bf16x8*)&B0[rowB];
        bfB = *(const bf16x8*)&B0[rowB + 512];
        STAGE(nbuf, 0, Agk);
        SB(); BAR(); LGKM0(); SB();
        __builtin_amdgcn_s_setprio(1);
        #pragma unroll
        for (int i = 0; i < 8; ++i) {
            acc[i][0] = __builtin_amdgcn_mfma_f32_16x16x32_bf16(af[i], bfA, acc[i][0], 0, 0, 0);
            acc[i][1] = __builtin_amdgcn_mfma_f32_16x16x32_bf16(af[i], bfB, acc[i][1], 0, 0, 0);
        }
        __builtin_amdgcn_s_setprio(0);
        SB(); BAR(); SB();

        // ---- ph2: klo, n23 ----
        bfA = *(const bf16x8*)&B0[rowB + 2*512];
        bfB = *(const bf16x8*)&B0[rowB + 3*512];
        STAGE(nbuf, 2, Bgk);
        SB(); BAR(); LGKM0(); SB();
        __builtin_amdgcn_s_setprio(1);
        #pragma unroll
        for (int i = 0; i < 8; ++i) {
            acc[i][2] = __builtin_amdgcn_mfma_f32_16x16x32_bf16(af[i], bfA, acc[i][2], 0, 0, 0);
            acc[i][3] = __builtin_amdgcn_mfma_f32_16x16x32_bf16(af[i], bfB, acc[i][3], 0, 0, 0);
        }
        __builtin_amdgcn_s_setprio(0);
        SB(); VM(4); BAR(); SB();      // khi(kt) ready for ph3

        // ---- ph3: khi, n01 ----
        #pragma unroll
        for (int i = 0; i < 8; ++i) af[i] = *(const bf16x8*)&A1[rowA + i*512];
        bfA = *(const bf16x8*)&B1[rowB];
        bfB = *(const bf16x8*)&B1[rowB + 512];
        STAGE(nbuf, 1, Agk + 32);
        SB(); BAR(); LGKM0(); SB();
        __builtin_amdgcn_s_setprio(1);
        #pragma unroll
        for (int i = 0; i < 8; ++i) {
            acc[i][0] = __builtin_amdgcn_mfma_f32_16x16x32_bf16(af[i], bfA, acc[i][0], 0, 0, 0);
            acc[i][1] = __builtin_amdgcn_mfma_f32_16x16x32_bf16(af[i], bfB, acc[i][1], 0, 0, 0);
        }
        __builtin_amdgcn_s_setprio(0);
        SB(); BAR(); SB();

        // ---- ph4: khi, n23 ----
        bfA = *(const bf16x8*)&B1[rowB + 2*512];
        bfB = *(const bf16x8*)&B1[rowB + 3*512];
        STAGE(nbuf, 3, Bgk + 32);
        SB(); BAR(); LGKM0(); SB();
        __builtin_amdgcn_s_setprio(1);
        #pragma unroll
        for (int i = 0; i < 8; ++i) {
            acc[i][2] = __builtin_amdgcn_mfma_f32_16x16x32_bf16(af[i], bfA, acc[i][2], 0, 0, 0);
            acc[i][3] = __builtin_amdgcn_mfma_f32_16x16x32_bf16(af[i], bfB, acc[i][3], 0, 0, 0);
        }
        __builtin_amdgcn_s_setprio(0);
        SB(); VM(4); BAR(); SB();      // klo(kt+1) ready for next ph1
    }

    // ---- last tile (kt = TK-1), peeled: no stages ----
    {
        const int buf = (TK - 1) & 1;
        const ushort* A0 = &L[buf][0][0];
        const ushort* A1 = &L[buf][1][0];
        const ushort* B0 = &L[buf][2][0];
        const ushort* B1 = &L[buf][3][0];

        // ph1 + ph2 (klo)
        #pragma unroll
        for (int i = 0; i < 8; ++i) af[i] = *(const bf16x8*)&A0[rowA + i*512];
        bfA = *(const bf16x8*)&B0[rowB];
        bfB = *(const bf16x8*)&B0[rowB + 512];
        #pragma unroll
        for (int i = 0; i < 8; ++i) {
            acc[i][0] = __builtin_amdgcn_mfma_f32_16x16x32_bf16(af[i], bfA, acc[i][0], 0, 0, 0);
            acc[i][1] = __builtin_amdgcn_mfma_f32_16x16x32_bf16(af[i], bfB, acc[i][1], 0, 0, 0);
        }
        bfA = *(const bf16x8*)&B0[rowB + 2*512];
        bfB = *(const bf16x8*)&B0[rowB + 3*512];
        #pragma unroll
        for (int i = 0; i < 8; ++i) {
            acc[i][2] = __builtin_amdgcn_mfma_f32_16x16x32_bf16(af[i], bfA, acc[i][2], 0, 0, 0);
            acc[i][3] = __builtin_amdgcn_mfma_f32_16x16x32_bf16(af[i], bfB, acc[i][3], 0, 0, 0);
        }
        VM(0);                        // drain khi(TK-1)
        BAR(); SB();
        // ph3 + ph4 (khi)
        #pragma unroll
        for (int i = 0; i < 8; ++i) af[i] = *(const bf16x8*)&A1[rowA + i*512];
        bfA = *(const bf16x8*)&B1[rowB];
        bfB = *(const bf16x8*)&B1[rowB + 512];
        #pragma unroll
        for (int i = 0; i < 8; ++i) {
            acc[i][0] = __builtin_amdgcn_mfma_f32_16x16x32_bf16(af[i], bfA, acc[i][0], 0, 0, 0);
            acc[i][1] = __builtin_amdgcn_mfma_f32_16x16x32_bf16(af[i], bfB, acc[i][1], 0, 0, 0);
        }
        bfA = *(const bf16x8*)&B1[rowB + 2*512];
        bfB = *(const bf16x8*)&B1[rowB + 3*512];
        #pragma unroll
        for (int i = 0; i < 8; ++i) {
            acc[i][2] = __builtin_amdgcn_mfma_f32_16x16x32_bf16(af[i], bfA, acc[i][2], 0, 0, 0);
            acc[i][3] = __builtin_amdgcn_mfma_f32_16x16x32_bf16(af[i], bfB, acc[i][3], 0, 0, 0);
        }
    }
#undef STAGE

    // epilogue: + bias + residual x
    #pragma unroll
    for (int m = 0; m < 8; ++m) {
        int ro_base = o0 + wr*128 + m*16 + ((l >> 4) << 2);
        #pragma unroll
        for (int n = 0; n < 4; ++n) {
            int col = hw0 + wc*64 + n*16 + (l & 15);
            #pragma unroll
            for (int r = 0; r < 4; ++r) {
                int ro = ro_base + r;
                size_t idx = (size_t)b*NC*HWD + (size_t)ro*HWD + col;
                out[idx] = acc[m][n][r] + bias[ro] + x[idx];
            }
        }
    }
}

extern "C" void kernel_launch(void* const* d_in, const int* in_sizes, int n_in,
                              void* d_out, int out_size, void* d_ws, size_t ws_size,
                              hipStream_t stream) {
    const float* x       = (const float*)d_in[0];
    const float* pos_dec = (const float*)d_in[1];
    const float* len_dec = (const float*)d_in[2];
    const float* conv_w  = (const float*)d_in[3];
    const float* conv_b  = (const float*)d_in[4];
    float* out = (float*)d_out;

    char* ws = (char*)d_ws;
    ushort* featT = (ushort*)ws;                                   // 94,371,840 B
    ushort* wb    = (ushort*)(ws + FEAT_BYTES);                    // 3,276,800 B
    float*  part  = (float*)(ws + FEAT_BYTES + WB_BYTES);          // 138,240 B
    float*  coef  = part + PART_FLOATS;                            // 1,920 B

    k_dots <<<dim3(BB*CH2), 256, 0, stream>>>(x, part);
    k_coef <<<dim3(1), 256, 0, stream>>>(part, pos_dec, len_dec, coef);
    k_wconv<<<dim3(1600), 256, 0, stream>>>(conv_w, wb);
    k_feat <<<dim3(72, BB), 256, 0, stream>>>(x, coef, featT);
    k_gemm <<<dim3(720), 512, 0, stream>>>(wb, featT, conv_b, x, out);
}